// Round 1
// 428.249 us; speedup vs baseline: 1.0023x; 1.0023x over previous
//
#include <hip/hip_runtime.h>

typedef unsigned int u32;
typedef __attribute__((ext_vector_type(4))) float float4v;

// Problem-fixed geometry: x (1,32,128,128,128) f32 -> 8 subbands (1,32,64,64,64) f32.
#define IN_ROW    128u
#define IN_PLANE  16384u      // 128*128
#define IN_CHAN   2097152u    // 128^3
#define OUT_ROW   64u
#define OUT_PLANE 4096u       // 64*64
#define OUT_CHAN  262144u     // 64^3
#define OUT_SUB   8388608u    // 32*64^3 elements per subband

// Non-temporal global access: both streams are touch-once (no reuse anywhere),
// so mark them evict-first in L2. nt does not bypass L1, so the a/b loads that
// share 64B lines still merge.
__device__ __forceinline__ float4v ntload(const float* p) {
    return __builtin_nontemporal_load((const float4v*)p);
}
__device__ __forceinline__ void ntstore(float* p, float4v v) {
    __builtin_nontemporal_store(v, (float4v*)p);
}

// k-stage of the Haar butterfly: 8 f32 along W (two float4) -> 4 sums, 4 diffs.
__device__ __forceinline__ void kstage(float4v a, float4v b, float4v& s, float4v& t) {
    s = (float4v){a.x + a.y, a.z + a.w, b.x + b.y, b.z + b.w};   // L_k = x0 + x1
    t = (float4v){a.y - a.x, a.w - a.z, b.y - b.x, b.w - b.z};   // H_k = x1 - x0
}

// One thread = 4 consecutive output-W positions for all 8 subbands.
// Reads 4 rows x 32B (2x dwordx4), writes 8x16B f32. Memory-bound streaming.
__global__ __launch_bounds__(256) void haar8_kernel(const float* __restrict__ x,
                                                    float* __restrict__ out) {
    const u32 tid = blockIdx.x * 256u + threadIdx.x;
    const u32 w4 = tid & 15u;          // 16 chunks of 4 outputs along W
    const u32 h  = (tid >> 4) & 63u;
    const u32 d  = (tid >> 10) & 63u;
    const u32 c  = tid >> 16;          // 0..31

    const float* p = x + (size_t)c * IN_CHAN + (size_t)(2u * d) * IN_PLANE
                       + (size_t)(2u * h) * IN_ROW + (size_t)(w4 * 8u);

    // Issue all 8 loads before any compute (max MLP).
    const float4v a00 = ntload(p);
    const float4v b00 = ntload(p + 4u);
    const float4v a01 = ntload(p + IN_ROW);
    const float4v b01 = ntload(p + IN_ROW + 4u);
    const float4v a10 = ntload(p + IN_PLANE);
    const float4v b10 = ntload(p + IN_PLANE + 4u);
    const float4v a11 = ntload(p + IN_PLANE + IN_ROW);
    const float4v b11 = ntload(p + IN_PLANE + IN_ROW + 4u);

    float4v s00, t00, s01, t01, s10, t10, s11, t11;
    kstage(a00, b00, s00, t00);
    kstage(a01, b01, s01, t01);
    kstage(a10, b10, s10, t10);
    kstage(a11, b11, s11, t11);

    // j-stage (H dimension)
    const float4v P0 = s00 + s01, Q0 = s01 - s00, R0 = t00 + t01, S0 = t01 - t00;
    const float4v P1 = s10 + s11, Q1 = s11 - s10, R1 = t10 + t11, S1 = t11 - t10;

    const float SC = 0.35355339059327373f;   // (1/sqrt(2))^3

    const u32 ob = c * OUT_CHAN + d * OUT_PLANE + h * OUT_ROW + w4 * 4u;
    // i-stage (D dimension) + scale. Subband order: LLL..HHH (f = 4i+2j+k).
    ntstore(out + ob + 0u * OUT_SUB, (P0 + P1) * SC);  // LLL
    ntstore(out + ob + 1u * OUT_SUB, (R0 + R1) * SC);  // LLH
    ntstore(out + ob + 2u * OUT_SUB, (Q0 + Q1) * SC);  // LHL
    ntstore(out + ob + 3u * OUT_SUB, (S0 + S1) * SC);  // LHH
    ntstore(out + ob + 4u * OUT_SUB, (P1 - P0) * SC);  // HLL
    ntstore(out + ob + 5u * OUT_SUB, (R1 - R0) * SC);  // HLH
    ntstore(out + ob + 6u * OUT_SUB, (Q1 - Q0) * SC);  // HHL
    ntstore(out + ob + 7u * OUT_SUB, (S1 - S0) * SC);  // HHH
}

extern "C" void kernel_launch(void* const* d_in, const int* in_sizes, int n_in,
                              void* d_out, int out_size, void* d_ws, size_t ws_size,
                              hipStream_t stream) {
    const float* x = (const float*)d_in[0];
    float* out     = (float*)d_out;
    // 32 * 64 * 64 * 16 threads = 2,097,152 -> exact cover, no bounds check.
    haar8_kernel<<<8192, 256, 0, stream>>>(x, out);
}